// Round 1
// baseline (333.359 us; speedup 1.0000x reference)
//
#include <hip/hip_runtime.h>
#include <hip/hip_bf16.h>

// out[i, r, c] = dot(q[i, r, :], e[h, L-1-(r-c), :])  for c <= r, else 0
// T[r, n] = q[r,:] . e_rev[n,:]  (n = r - c).
//
// Barrier-free restructure: each WAVE independently computes a 16x64 output
// tile (rows s..s+15, cols c0..c0+63).  Needed diagonals n span
// [M-63, M+15], M = s - c0 -> 5 MFMA n-subtiles covering [M-64, M+16).
// The strip is staged into a per-wave SKEWED LDS region:
//     T[s+rr, n] -> lds[w][rr][g],  g = n - rr + (79 - M)
// so the output read column g = 79 - (c - c0) is row-independent -> the
// store phase reads an aligned f32x4 (reversed) and writes one 16 B
// nontemporal store per thread per iteration.  No __syncthreads anywhere
// (each wave reads only its own LDS slice; lgkmcnt suffices).
// Zero-fill of the mirrored strictly-upper tile is issued LAST so its HBM
// writes never sit ahead of load waits in the in-order vmcnt FIFO.

typedef __bf16 bf16x8 __attribute__((ext_vector_type(8)));
typedef float  f32x4  __attribute__((ext_vector_type(4)));
typedef float  f32x8  __attribute__((ext_vector_type(8)));

constexpr int L   = 2048;
constexpr int D   = 64;
constexpr int NT  = 32;     // tiles per side
constexpr int LDW = 100;    // LDS row stride in floats (width 95 + pad)

__device__ __forceinline__ bf16x8 load_cvt8(const float* __restrict__ p) {
  f32x8 v = *(const f32x8*)p;       // 2x global_load_dwordx4
  bf16x8 r;
#pragma unroll
  for (int k = 0; k < 8; ++k) r[k] = (__bf16)v[k];
  return r;
}

__global__ __launch_bounds__(256) void skew_mfma(const float* __restrict__ q,
                                                 const float* __restrict__ e,
                                                 float* __restrict__ out) {
  const int tid  = threadIdx.x;
  const int lane = tid & 63;
  const int w    = tid >> 6;        // wave 0..3
  const int ln   = lane & 15;
  const int quad = lane >> 4;
  const int i = blockIdx.x;         // bh index, h = i & 7
  const int p = blockIdx.y;         // lower-triangle pair index, 0..527
  const int h = i & 7;

  // decode p -> (x, j), j <= x (row-major over lower triangle)
  float tf = __builtin_sqrtf(8.f * (float)p + 1.f);
  int x = (int)((tf - 1.f) * 0.5f);
  if ((x + 1) * (x + 2) / 2 <= p) ++x;
  if (x * (x + 1) / 2 > p) --x;
  const int j  = p - x * (x + 1) / 2;
  const int r0 = x << 6;
  const int c0 = j << 6;
  const bool diag = (j == x);       // block-uniform

  __shared__ __align__(16) float lds[4 * 16 * LDW];   // 25.6 KB, per-wave slices

  float* obase = out + (size_t)i * L * L;

  const int s    = r0 + (w << 4);   // this wave's first output row
  const int M    = s - c0;          // diagonal offset; n in [M-64, M+16)
  const int tmin = diag ? (4 - w) : 0;   // skip all-junk (n<0) subtiles on diag

  // ---- A fragments: lane holds q[s+ln][quad*8 + k] ----
  const float* qp = q + ((size_t)(i * L + s + ln)) * D + (quad << 3);
  bf16x8 a0 = load_cvt8(qp);
  bf16x8 a1 = load_cvt8(qp + 32);

  // ---- B loads + MFMA: subtile t covers n = M-64+16t+ln ----
  // erow = L-1-n = 2111 - M - 16t - ln  (always in [0, L-1] given tmin)
  const float* ep = e + ((size_t)(h * L + (2111 - M - ln))) * D + (quad << 3);
  f32x4 acc[5];
#pragma unroll
  for (int t = 0; t < 5; ++t) {
    if (t < tmin) continue;
    const float* ept = ep - (t << 10);       // -16t e-rows (1024 floats)
    bf16x8 b0 = load_cvt8(ept);
    bf16x8 b1 = load_cvt8(ept + 32);
    f32x4 z = {0.f, 0.f, 0.f, 0.f};
    z      = __builtin_amdgcn_mfma_f32_16x16x32_bf16(a0, b0, z, 0, 0, 0);
    acc[t] = __builtin_amdgcn_mfma_f32_16x16x32_bf16(a1, b1, z, 0, 0, 0);
  }

  // ---- skewed LDS stage ----
  // C-frag: row = quad*4 + jr, col n = (M-64+16t) + ln
  // lds float index = w*16*LDW + row*LDW + g,  g = 15 + 16t + ln - 4*quad - jr
  //                 = w*1600 + quad*(4*LDW-4) + jr*(LDW-1) + 16t + ln + 15
  const int lbase = w * (16 * LDW) + quad * (4 * LDW - 4) + ln + 15;
#pragma unroll
  for (int t = 0; t < 5; ++t) {
    if (t < tmin) continue;
#pragma unroll
    for (int jr = 0; jr < 4; ++jr)
      lds[lbase + jr * (LDW - 1) + (t << 4)] = acc[t][jr];
  }

  // ---- diagonal-aligned reads + 16 B stores ----
  // (rr, jj): out row s+rr, cols c0+4*jj..+3; read g = 79-dc -> f32x4 at
  // base col 76-4*jj (16 B aligned), reversed.  Diag: mask c > r to 0
  // (also covers garbage read from skipped subtiles' LDS area).
#pragma unroll
  for (int it = 0; it < 4; ++it) {
    const int idx = (it << 6) + lane;
    const int rr  = idx >> 4;
    const int jj  = idx & 15;
    const f32x4 v = *(const f32x4*)&lds[w * (16 * LDW) + rr * LDW + 76 - (jj << 2)];
    f32x4 o = { v[3], v[2], v[1], v[0] };
    if (diag) {
      const int lim = (w << 4) + rr - (jj << 2);   // t2 > lim  ->  c > r
#pragma unroll
      for (int t2 = 0; t2 < 4; ++t2) if (t2 > lim) o[t2] = 0.f;
    }
    __builtin_nontemporal_store(
        o, (f32x4*)(obase + (size_t)(s + rr) * L + c0 + (jj << 2)));
  }

  // ---- mirrored strictly-upper tile: pure zero-fill, issued LAST ----
  if (!diag) {
    const int r0z = (NT - 1 - x) << 6;
    const int c0z = (NT - 1 - j) << 6;
    const f32x4 zz = {0.f, 0.f, 0.f, 0.f};
#pragma unroll
    for (int it = 0; it < 4; ++it) {
      const int idx = (it << 8) + tid;     // 0..1023
      const int rr  = idx >> 4;
      const int jj  = idx & 15;
      __builtin_nontemporal_store(
          zz, (f32x4*)(obase + (size_t)(r0z + rr) * L + c0z + (jj << 2)));
    }
  }
}

extern "C" void kernel_launch(void* const* d_in, const int* in_sizes, int n_in,
                              void* d_out, int out_size, void* d_ws, size_t ws_size,
                              hipStream_t stream) {
  const float* q = (const float*)d_in[0];   // (2, 8, 2048, 64) fp32
  const float* e = (const float*)d_in[1];   // (8, 2048, 64) fp32
  float* out = (float*)d_out;               // (2, 8, 2048, 2048) fp32

  dim3 grid(16, NT * (NT + 1) / 2);   // (bh, lower-triangle pair) = (16, 528)
  skew_mfma<<<grid, 256, 0, stream>>>(q, e, out);
}

// Round 2
// 321.293 us; speedup vs baseline: 1.0376x; 1.0376x over previous
//
#include <hip/hip_runtime.h>
#include <hip/hip_bf16.h>

// out[i, r, c] = dot(q[i, r, :], e[h, L-1-(r-c), :])  for c <= r, else 0
// T[r, n] = q[r,:] . e_rev[n,:]  (n = r - c).
//
// ROW-LINEAR retile: each wave owns 16-row strips and sweeps the full row
// left->right in 64-col chunks, so the HBM write stream per wave is linear
// (like the 6.4 TB/s fill), not 256 B segments scattered across 8448 tiles.
// Upper-triangle zeros are the natural tail of the same linear sweep.
//
// Per chunk (cols [c0, c0+64)), diagonals n = r-c span [M-63, M+15],
// M = s0-c0 >= 0 -> 5 MFMA n-subtiles covering [M-64, M+16) (subtiles with
// all n<0 skipped via tmin; partial subtile starts exactly at n=0 so no OOB
// e reads).  The strip is staged into a per-wave SKEWED LDS slice:
//     T[s0+rr, n] -> ldsw[rr][g],  g = n - rr + (79 - M)
// so the output read column g = 79 - (c - c0) is row-independent -> aligned
// f32x4 read (reversed) -> one 16 B nontemporal store per thread per iter.
// No __syncthreads anywhere (waves touch only their own LDS slice).
//
// Balance: strip k (nch = k/4+1 compute chunks) pairs with strip 127-k
// (nch = 32-k/4) -> every pair = 33 compute + 31 zero chunks.  Each pair is
// split across 2 waves by chunk parity -> 2048 identical waves.
// Grid 16 x 16, 512 threads (8 waves): 1 block/CU, 2 waves/SIMD.

typedef __bf16 bf16x8 __attribute__((ext_vector_type(8)));
typedef float  f32x4  __attribute__((ext_vector_type(4)));
typedef float  f32x8  __attribute__((ext_vector_type(8)));

constexpr int L   = 2048;
constexpr int D   = 64;
constexpr int LDW = 100;    // LDS row stride in floats (g in [0,94] + pad)

__device__ __forceinline__ bf16x8 load_cvt8(const float* __restrict__ p) {
  f32x8 v = *(const f32x8*)p;       // 2x global_load_dwordx4
  bf16x8 r;
#pragma unroll
  for (int k = 0; k < 8; ++k) r[k] = (__bf16)v[k];
  return r;
}

__global__ __launch_bounds__(512) void skew_rows(const float* __restrict__ q,
                                                 const float* __restrict__ e,
                                                 float* __restrict__ out) {
  const int tid  = threadIdx.x;
  const int lane = tid & 63;
  const int w    = tid >> 6;        // wave 0..7
  const int ln   = lane & 15;
  const int quad = lane >> 4;
  const int i = blockIdx.x;         // bh index, h = i & 7
  const int h = i & 7;
  const int pp     = blockIdx.y * 4 + (w >> 1);   // strip pair 0..63
  const int parity = w & 1;                       // chunk parity

  __shared__ __align__(16) float lds[8 * 16 * LDW];   // 51.2 KB, per-wave slices
  float* ldsw  = &lds[w * (16 * LDW)];
  float* obase = out + (size_t)i * L * L;

#pragma unroll 1
  for (int sp = 0; sp < 2; ++sp) {
    const int sidx = sp ? (127 - pp) : pp;   // strip index 0..127
    const int s0   = sidx << 4;              // first row of strip
    const int nch  = (s0 >> 6) + 1;          // chunks containing lower-tri data

    // ---- A fragments: lane holds q[s0+ln][quad*8 + k] (held across sweep) ----
    const float* qp = q + ((size_t)(i * L + s0 + ln)) * D + (quad << 3);
    const bf16x8 a0 = load_cvt8(qp);
    const bf16x8 a1 = load_cvt8(qp + 32);

#pragma unroll 1
    for (int ch = parity; ch < 32; ch += 2) {
      const int c0 = ch << 6;
      float* orow = obase + (size_t)s0 * L + c0;

      if (ch < nch) {
        // ---- compute chunk ----
        const int M    = s0 - c0;                          // >= 0
        const int tmin = (M >= 64) ? 0 : ((64 - M) >> 4);  // skip all-(n<0) subtiles

        // B loads + MFMA: subtile t covers n = M-64+16t+ln, erow = L-1-n
        const float* ep = e + ((size_t)(h * L + (2111 - M - ln))) * D + (quad << 3);
        f32x4 acc[5];
#pragma unroll
        for (int t = 0; t < 5; ++t) {
          if (t < tmin) continue;
          const float* ept = ep - (t << 10);     // -16t e-rows (1024 floats)
          bf16x8 b0 = load_cvt8(ept);
          bf16x8 b1 = load_cvt8(ept + 32);
          f32x4 z = {0.f, 0.f, 0.f, 0.f};
          z      = __builtin_amdgcn_mfma_f32_16x16x32_bf16(a0, b0, z, 0, 0, 0);
          acc[t] = __builtin_amdgcn_mfma_f32_16x16x32_bf16(a1, b1, z, 0, 0, 0);
        }

        // skewed LDS stage: C-frag row = quad*4+jr, col n = (M-64+16t)+ln
        // float idx = row*LDW + g, g = 15 + 16t + ln - 4*quad - jr
        const int lbase = quad * (4 * LDW - 4) + ln + 15;
#pragma unroll
        for (int t = 0; t < 5; ++t) {
          if (t < tmin) continue;
#pragma unroll
          for (int jr = 0; jr < 4; ++jr)
            ldsw[lbase + jr * (LDW - 1) + (t << 4)] = acc[t][jr];
        }

        // diagonal-aligned reads + 16 B stores; mask c>r iff chunk hits diag.
        // (skipped-subtile stale data lies exactly in the masked c>r region)
        const bool mask = (M < 64);
#pragma unroll
        for (int it = 0; it < 4; ++it) {
          const int idx = (it << 6) + lane;
          const int rr  = idx >> 4;
          const int jj  = idx & 15;
          const f32x4 v = *(const f32x4*)&ldsw[rr * LDW + 76 - (jj << 2)];
          f32x4 o = { v[3], v[2], v[1], v[0] };
          if (mask) {
            const int lim = M + rr - (jj << 2);   // t2 > lim  ->  c > r
#pragma unroll
            for (int t2 = 0; t2 < 4; ++t2) if (t2 > lim) o[t2] = 0.f;
          }
          __builtin_nontemporal_store(
              o, (f32x4*)(orow + (size_t)rr * L + (jj << 2)));
        }
      } else {
        // ---- pure zero chunk (upper triangle) ----
        const f32x4 zz = {0.f, 0.f, 0.f, 0.f};
#pragma unroll
        for (int it = 0; it < 4; ++it) {
          const int idx = (it << 6) + lane;
          const int rr  = idx >> 4;
          const int jj  = idx & 15;
          __builtin_nontemporal_store(
              zz, (f32x4*)(orow + (size_t)rr * L + (jj << 2)));
        }
      }
    }
  }
}

extern "C" void kernel_launch(void* const* d_in, const int* in_sizes, int n_in,
                              void* d_out, int out_size, void* d_ws, size_t ws_size,
                              hipStream_t stream) {
  const float* q = (const float*)d_in[0];   // (2, 8, 2048, 64) fp32
  const float* e = (const float*)d_in[1];   // (8, 2048, 64) fp32
  float* out = (float*)d_out;               // (2, 8, 2048, 2048) fp32

  dim3 grid(16, 16);   // (bh, 4-pair group) -> 256 blocks, 8 waves each
  skew_rows<<<grid, 512, 0, stream>>>(q, e, out);
}